// Round 1
// 94.951 us; speedup vs baseline: 1.0447x; 1.0447x over previous
//
#include <hip/hip_runtime.h>
#include <math.h>

// ---------------------------------------------------------------------------
// NFFT forward (type-2): f_hat (B,C,256,256 complex) -> samples at M points.
// 3 dispatches (R8: cooperative grid.sync is catastrophically slow on 8 XCDs):
//   rows: channel-merged fused deconvolve/pad/fftshift + 512-pt row FFT.
//         Both channels of one b-image ride in a float4 (re0,im0,re1,im1).
//         R10: stage-0 fused into staging (each bit-reversed stage-0 pair has
//         exactly one nonzero input -> write (v, +/-v) directly, no zero fill,
//         8 FFT stages instead of 9).
//   cols: 4-column tiles, float4 butterflies; R10: stage-0 fused into the load
//         (zero middle rows never touch LDS), stage loop fully unrolled with
//         hoisted twiddles (36 -> 11 sincos/thread; pos identical across the
//         4 butterflies for half<=64). Output packed bf16x4 into the
//         never-written middle-row region of G32 (exact 2 MB/image fit).
//   gather: 8 lanes per (b,point); per row-tap ONE 8B load/lane yields both
//         channels. R10: weight path uses rsq (a and 1/a from one op), __expf
//         and v_rcp instead of libm expf + two precise divides.
// Shift algebra: ifftshift(FFT(fftshift(p)))[(ind+256)%512] == FFT(fftshift(p))[ind&511].
// Output PLANAR: real plane (B,C,M) then imag plane.
// R4: no forced __launch_bounds__ minima (spill -> dead kernel).
// R5: coalesce scattered gathers. R7: ~12-15us per dispatch boundary.
// ---------------------------------------------------------------------------

#define NGRID 512
#define NSMALL 256
#define MW 4
#define BB 2
#define CC 2
#define MPTS 200000
#define PLANE (BB * CC * MPTS)   // imag-plane offset in floats
#define LPAD4 513                // LDS pitch in float4 (breaks pow2 banking)
#define IMG4 (NGRID * NGRID)     // float4 elems per b-image in G32
// G16 (uint2 units): image b's packed grid lives in G32's middle rows
#define G16OFF(b) ((size_t)(b) * 524288 + 131072)

// I0(z) asymptotic series, valid z > 8 (our z in [17.7, 18.9])
__device__ __forceinline__ float nfft29781_i0_large(float z) {
    float inv = __builtin_amdgcn_rcpf(z);
    float p = 1.0f + inv * (0.125f + inv * (0.0703125f
              + inv * (0.0732421875f + inv * 0.112152099609375f)));
    return __expf(z) * rsqrtf(2.0f * (float)M_PI * z) * p;
}

__device__ __forceinline__ int nfft29781_brev9(int v) {
    return (int)(__brev((unsigned)v) >> 23);
}

__device__ __forceinline__ unsigned nfft29781_bf16pack(float a, float b) {
    unsigned ua = __float_as_uint(a);
    ua += 0x7FFFu + ((ua >> 16) & 1u);           // RNE
    unsigned ub = __float_as_uint(b);
    ub += 0x7FFFu + ((ub >> 16) & 1u);
    return (ua >> 16) | (ub & 0xFFFF0000u);
}

// ---------------------------------------------------------------------------
// Rows: one block per (b, a1), a1 in [0,256) = f_hat row; both channels.
// Staged col j2 = (tid<128)? tid : tid+256 (always outside [128,384)).
// Stage 0 fused: pair partner is always zero -> write (v, v) or (v, -v).
// ---------------------------------------------------------------------------
__global__ __launch_bounds__(256) void nfft29781_rows2(const float* __restrict__ fr,
                                                       const float* __restrict__ fi,
                                                       float4* __restrict__ G32) {
    __shared__ float4 s[NGRID];
    int tid = threadIdx.x;
    int b   = blockIdx.x >> 8;
    int a1  = blockIdx.x & 255;

    const float bcon  = 1.5f * (float)M_PI;
    const float scale = 2.0f * (float)M_PI / (float)NGRID;
    float k1 = (float)(a1 - 128) * scale;
    float p1 = nfft29781_i0_large((float)MW * sqrtf(bcon * bcon - k1 * k1));

    int a2 = tid ^ 128;
    float k2 = (float)(a2 - 128) * scale;
    float p2 = nfft29781_i0_large((float)MW * sqrtf(bcon * bcon - k2 * k2));
    float invp = __builtin_amdgcn_rcpf(p1 * p2);

    size_t s0 = ((size_t)(b * CC + 0) * NSMALL + a1) * NSMALL + a2;
    size_t s1 = ((size_t)(b * CC + 1) * NSMALL + a1) * NSMALL + a2;
    float4 v = make_float4(fr[s0] * invp, fi[s0] * invp,
                           fr[s1] * invp, fi[s1] * invp);

    // fused stage 0: nonzero staged col j2v pairs with an all-zero partner.
    // p even (j2v<256): s[p]=v, s[p+1]=v.  p odd (j2v>=256): s[p-1]=v, s[p]=-v.
    int j2v = (tid < 128) ? tid : tid + 256;
    int pidx = nfft29781_brev9(j2v);
    int pe = pidx & ~1;
    s[pe]     = v;
    s[pe + 1] = (pidx & 1) ? make_float4(-v.x, -v.y, -v.z, -v.w) : v;
    __syncthreads();

    // stages 1..8
    #pragma unroll
    for (int st = 1; st < 9; ++st) {
        int half = 1 << st;
        int pos = tid & (half - 1);
        int i0 = ((tid >> st) << (st + 1)) + pos;
        int i1 = i0 + half;
        float sn, cs;
        if (st == 1) {                          // twiddle is 1 or -i: no sincos
            cs = pos ? 0.0f : 1.0f;
            sn = pos ? -1.0f : 0.0f;
        } else {
            float ang = -(float)M_PI * (float)pos / (float)half;
            __sincosf(ang, &sn, &cs);
        }
        float4 a = s[i0];
        float4 bq = s[i1];
        float4 tw;
        tw.x = bq.x * cs - bq.y * sn;  tw.y = bq.x * sn + bq.y * cs;
        tw.z = bq.z * cs - bq.w * sn;  tw.w = bq.z * sn + bq.w * cs;
        s[i0] = make_float4(a.x + tw.x, a.y + tw.y, a.z + tw.z, a.w + tw.w);
        s[i1] = make_float4(a.x - tw.x, a.y - tw.y, a.z - tw.z, a.w - tw.w);
        __syncthreads();
    }

    int j1 = (a1 < 128) ? a1 + 384 : a1 - 128;      // staged row (fftshift fold)
    float4* Gb = G32 + (size_t)b * IMG4 + (size_t)j1 * NGRID;
    Gb[tid]       = s[tid];
    Gb[tid + 256] = s[tid + 256];
}

// ---------------------------------------------------------------------------
// Cols: one block per (b, 4-col group); 256 blocks. Reads the 256 nonzero
// rows (fp32 float4); stage 0 fused into staging (middle-row zeros never
// touch LDS); 8 unrolled stages with hoisted/CSE'd twiddles; packs result to
// bf16x4 into G32's middle-row region (disjoint from reads).
// ---------------------------------------------------------------------------
__global__ __launch_bounds__(256) void nfft29781_cols2(float4* __restrict__ G32) {
    __shared__ float4 s[4 * LPAD4];                 // 32.8 KB
    int tid  = threadIdx.x;
    int b    = blockIdx.x >> 7;
    int col0 = (blockIdx.x & 127) << 2;
    const float4* Gb = G32 + (size_t)b * IMG4;

    // load 256 nonzero rows x 4 cols; fused stage 0: each bit-reversed
    // stage-0 pair (r, r+256) has exactly one nonzero member.
    #pragma unroll
    for (int it = 0; it < 4; ++it) {
        int e  = it * 256 + tid;                    // 0..1023
        int cp = e & 3;
        int q  = e >> 2;                            // 0..255
        int r  = (q < 128) ? q : q + 256;           // nonzero row
        float4 v = Gb[(size_t)r * NGRID + col0 + cp];
        int pidx = nfft29781_brev9(r);
        int pe = pidx & ~1;
        float4* scw = s + cp * LPAD4;
        scw[pe]     = v;
        scw[pe + 1] = (pidx & 1) ? make_float4(-v.x, -v.y, -v.z, -v.w) : v;
    }
    __syncthreads();

    // 4 column-FFTs in parallel: c owns a column, w does 4 butterflies/stage.
    // Stage loop fully unrolled: half compile-time, twiddles hoisted.
    // half<=64: pos identical for all k (64k % half == 0) -> 1 sincos.
    // half==128: 2 distinct. half==256: 4 distinct.  Total 11 sincos.
    int c = tid & 3;
    int w = tid >> 2;                               // 0..63
    float4* sc = s + c * LPAD4;
    #pragma unroll
    for (int st = 1; st < 9; ++st) {
        const int half = 1 << st;
        float csk[4], snk[4];
        if (st <= 6) {
            int pos = w & (half - 1);
            float sn, cs;
            if (st == 1) {                          // twiddle 1 or -i
                cs = pos ? 0.0f : 1.0f;
                sn = pos ? -1.0f : 0.0f;
            } else {
                float ang = -(float)M_PI * (float)pos / (float)half;
                __sincosf(ang, &sn, &cs);
            }
            csk[0] = csk[1] = csk[2] = csk[3] = cs;
            snk[0] = snk[1] = snk[2] = snk[3] = sn;
        } else if (st == 7) {
            #pragma unroll
            for (int k = 0; k < 2; ++k) {
                int pos = (w + (k << 6)) & 127;
                float ang = -(float)M_PI * (float)pos / 128.0f;
                __sincosf(ang, &snk[k], &csk[k]);
            }
            csk[2] = csk[0]; snk[2] = snk[0];
            csk[3] = csk[1]; snk[3] = snk[1];
        } else {
            #pragma unroll
            for (int k = 0; k < 4; ++k) {
                int pos = w + (k << 6);
                float ang = -(float)M_PI * (float)pos / 256.0f;
                __sincosf(ang, &snk[k], &csk[k]);
            }
        }
        #pragma unroll
        for (int k = 0; k < 4; ++k) {
            int bf  = w + (k << 6);                 // 0..255
            int pos = bf & (half - 1);
            int i0  = ((bf >> st) << (st + 1)) + pos;
            int i1  = i0 + half;
            float cs = csk[k], sn = snk[k];
            float4 a = sc[i0];
            float4 bb = sc[i1];
            float4 tw;
            tw.x = bb.x * cs - bb.y * sn;  tw.y = bb.x * sn + bb.y * cs;
            tw.z = bb.z * cs - bb.w * sn;  tw.w = bb.z * sn + bb.w * cs;
            sc[i0] = make_float4(a.x + tw.x, a.y + tw.y, a.z + tw.z, a.w + tw.w);
            sc[i1] = make_float4(a.x - tw.x, a.y - tw.y, a.z - tw.z, a.w - tw.w);
        }
        __syncthreads();
    }

    // pack + write all 512 rows x 4 cols into the middle-row region (uint2)
    uint2* G16 = (uint2*)G32 + G16OFF(b);
    #pragma unroll
    for (int it = 0; it < 8; ++it) {
        int e  = it * 256 + tid;                    // 0..2047
        int cp = e & 3;
        int r  = e >> 2;                            // 0..511
        float4 v = s[cp * LPAD4 + r];
        uint2 pk;
        pk.x = nfft29781_bf16pack(v.x, v.y);        // ch0 re|im
        pk.y = nfft29781_bf16pack(v.z, v.w);        // ch1 re|im
        G16[(size_t)r * NGRID + col0 + cp] = pk;
    }
}

// ---------------------------------------------------------------------------
// Gather: 8 lanes per (b,point); lane j owns column-tap j. Per row-tap ONE
// 8B load/lane -> both channels (bf16x4). Weights computed once per group,
// w0[i] broadcast via __shfl; 3-stage __shfl_xor sums; lane 0 writes planar.
// Weight sequence bit-matches reference ceil(x*n)-m. R10: rsq gives a and
// 1/a together; __expf + v_rcp replace libm expf + 2 precise divides.
// ---------------------------------------------------------------------------
__global__ __launch_bounds__(256) void nfft29781_gather_bf16(const float* __restrict__ x,
                                                             const uint2* __restrict__ G16base,
                                                             float* __restrict__ out,
                                                             int out_elems) {
    int t  = blockIdx.x * blockDim.x + threadIdx.x;
    int j  = t & 7;                  // my column tap
    int pp = t >> 3;                 // (b, point) id — shared by 8 group lanes
    if (pp >= BB * MPTS) return;
    int b  = (pp >= MPTS) ? 1 : 0;
    int pt = pp - b * MPTS;

    float u0 = x[(size_t)pp * 2 + 0] * (float)NGRID;   // broadcast within group
    float u1 = x[(size_t)pp * 2 + 1] * (float)NGRID;

    float c0 = ceilf(u0), c1 = ceilf(u1);
    int base0 = (int)c0 - MW;
    int base1 = (int)c1 - MW;
    float d0 = c0 - u0, d1 = c1 - u1;

    const float bw = 1.5f * (float)M_PI;
    const float invpi = 1.0f / (float)M_PI;
    float w0m, w1m;   // my dim-0 / dim-1 tap-j weights
    {
        float nk = (float)(MW - j) - d0;
        float tt = (float)(MW * MW) - nk * nk;
        w0m = 0.0f;
        if (tt > 0.0f) {
            float ra = __builtin_amdgcn_rsqf(tt);    // 1/a
            float a  = tt * ra;                      // a = sqrt(tt)
            float e  = __expf(bw * a);
            w0m = (e - __builtin_amdgcn_rcpf(e)) * (0.5f * invpi) * ra;
        }
        nk = (float)(MW - j) - d1;
        tt = (float)(MW * MW) - nk * nk;
        w1m = 0.0f;
        if (tt > 0.0f) {
            float ra = __builtin_amdgcn_rsqf(tt);
            float a  = tt * ra;
            float e  = __expf(bw * a);
            w1m = (e - __builtin_amdgcn_rcpf(e)) * (0.5f * invpi) * ra;
        }
    }

    const uint2* Gi = G16base + G16OFF(b);
    int cix = (base1 + j) & (NGRID - 1);
    int lanebase = (threadIdx.x & 63) & ~7;

    float a0x = 0.0f, a0y = 0.0f, a1x = 0.0f, a1y = 0.0f;
    #pragma unroll
    for (int i = 0; i < 8; ++i) {
        float w0i = __shfl(w0m, lanebase + i, 64);   // row-i weight
        uint2 g = Gi[(size_t)(((base0 + i) & (NGRID - 1)) << 9) + cix];
        float g0x = __uint_as_float(g.x << 16);
        float g0y = __uint_as_float(g.x & 0xFFFF0000u);
        float g1x = __uint_as_float(g.y << 16);
        float g1y = __uint_as_float(g.y & 0xFFFF0000u);
        a0x += w0i * g0x;  a0y += w0i * g0y;
        a1x += w0i * g1x;  a1y += w0i * g1y;
    }
    a0x *= w1m;  a0y *= w1m;  a1x *= w1m;  a1y *= w1m;

    #pragma unroll
    for (int msk = 1; msk < 8; msk <<= 1) {          // sum the 8 column taps
        a0x += __shfl_xor(a0x, msk, 64);
        a0y += __shfl_xor(a0y, msk, 64);
        a1x += __shfl_xor(a1x, msk, 64);
        a1y += __shfl_xor(a1y, msk, 64);
    }

    if (j == 0) {
        size_t o0 = (size_t)(b * CC) * MPTS + pt;    // channel 0
        size_t o1 = o0 + MPTS;                       // channel 1
        if (o0 < (size_t)out_elems)         out[o0]         = a0x;
        if (PLANE + o0 < (size_t)out_elems) out[PLANE + o0] = a0y;
        if (o1 < (size_t)out_elems)         out[o1]         = a1x;
        if (PLANE + o1 < (size_t)out_elems) out[PLANE + o1] = a1y;
    }
}

extern "C" void kernel_launch(void* const* d_in, const int* in_sizes, int n_in,
                              void* d_out, int out_size, void* d_ws, size_t ws_size,
                              hipStream_t stream) {
    (void)in_sizes; (void)n_in;
    const float* x  = (const float*)d_in[0];
    const float* fr = (const float*)d_in[1];
    const float* fi = (const float*)d_in[2];
    float*  out = (float*)d_out;
    float4* G32 = (float4*)d_ws;        // BB * 512*512 float4 = 8 MB

    const size_t fullBytes = (size_t)BB * IMG4 * sizeof(float4);
    if (ws_size < fullBytes) return;    // diagnostic no-op (ws proven >= 8 MB)

    nfft29781_rows2<<<BB * NSMALL, 256, 0, stream>>>(fr, fi, G32);
    nfft29781_cols2<<<BB * (NGRID / 4), 256, 0, stream>>>(G32);
    int gthreads = BB * MPTS * 8;       // 8 lanes per (b,point), both channels
    nfft29781_gather_bf16<<<(gthreads + 255) / 256, 256, 0, stream>>>(
        x, (const uint2*)d_ws, out, out_size);
}